// Round 6
// baseline (569.014 us; speedup 1.0000x reference)
//
#include <hip/hip_runtime.h>

#define B_ 32
#define T_ 1024
#define C_ 384
#define MAXLEN_ 2048
#define NBINS_ 255
#define WPK1 442368          /* 36*24*512 packed bf16 elems per weight */
#define ARS 392              /* A-tile row stride in bf16 (16B-aligned) */
#define TROWS 62             /* output rows per tile */
#define NTILE 17             /* ceil(1024/62) */

typedef __attribute__((ext_vector_type(8))) short short8v;   // 8 bf16 = 4 VGPRs
typedef __attribute__((ext_vector_type(4))) float floatx4;

__device__ __forceinline__ unsigned short f2bf(float f) {
    unsigned u = __float_as_uint(f);
    u += 0x7fffu + ((u >> 16) & 1u);   // RNE
    return (unsigned short)(u >> 16);
}

// hoist a wave-uniform pointer into SGPRs (saddr+voffset addressing, saves VGPRs)
__device__ __forceinline__ const unsigned short* rfl(const unsigned short* p) {
    unsigned long long u = (unsigned long long)p;
    unsigned lo = __builtin_amdgcn_readfirstlane((unsigned)u);
    unsigned hi = __builtin_amdgcn_readfirstlane((unsigned)(u >> 32));
    return (const unsigned short*)(((unsigned long long)hi << 32) | lo);
}

struct CvP {
    const float* xf;              // fp32 x input
    const unsigned short* wpk;    // packed weights; layer1 = +p*WPK1, layer2 = +(3+p)*WPK1
    const float* b1[3];  const float* g1[3];  const float* be1[3];
    const float* b2[3];  const float* g2[3];  const float* be2[3];
    const float* wo[3];  const float* bo[3];
    float* pred[3];
    const float* pbins; const float* pemb; const float* ptgt;  // p==2 fusion
};

// ---------------------------------------------------------------------------
// R14: fused layer1+layer2 (R13 structure) retiled so BOTH K-loops are
// exactly 4 m-tiles -> acc1 48 AGPR (was 60), afrag[4] (was [5]).
// R13 post-mortem: arch 84 + acc 60 = 144 regs -> 3 waves/SIMD -> an 8-wave
// block can't double up -> 1 block/CU (23.6% occ) -> 361 us despite the
// HBM win (WRITE 74MB -> 0.4MB). Register model (calibrated R9-R13):
// waves/SIMD = floor(512 / (arch + agpr)); need <=128 for 2 blocks/CU.
// Retile: output rows [t0, t0+61] (62 rows, 17 tiles/batch, grid 1632);
// h1 window [t0-1, t0+62] = 64 rows = 4 m-tiles; staged x = 66 rows.
// Layer2 m-tiles compute 64 rows, top 2 discarded (read stale-x As rows
// 64..65: finite garbage, per-row LN, rows discarded). Weight bases hoisted
// to SGPR via readfirstlane (saddr+voffset). Expect ~75 arch + 48 = ~123
// -> 4 waves/SIMD -> 2 blocks/CU with R13's traffic win intact.
// LDS: As 51.7KB + scratch 6.4KB = 58.2KB (<64K; 2 blocks = 116 <=160).
// ---------------------------------------------------------------------------
__global__ __launch_bounds__(512, 3) void conv_fused3(CvP P)
{
    __shared__ unsigned short As[66 * ARS];   // 51,744 B
    __shared__ float redS[8 * 64];            // 2 KB
    __shared__ float redQ[8 * 64];            // 2 KB
    __shared__ float prbuf[512];              // 2 KB
    __shared__ int embi[66];

    const int tid  = threadIdx.x;
    const int wave = tid >> 6;      // col group 0..7
    const int lane = tid & 63;
    const int lq   = lane >> 4;
    const int ln   = lane & 15;
    const int blk  = blockIdx.x;
    const int p    = blk / (B_ * NTILE);            // predictor 0..2
    const int rem  = blk - p * (B_ * NTILE);
    const int b    = rem / NTILE;
    const int k    = rem - b * NTILE;
    const int t0   = k * TROWS;                     // output rows [t0, t0+61]
    const int nb   = wave * 48;                     // 48 cols per wave

    // ---- layer1 B prefetch, steps 0 and 1 (SGPR base + voffset) ----
    const unsigned short* b1s = rfl(P.wpk + (size_t)p * WPK1 + wave * 1536);
    const int lo8 = lane * 8;
    short8v bA[3], bB[3];
#pragma unroll
    for (int nt = 0; nt < 3; ++nt) {
        bA[nt] = *(const short8v*)(b1s + lo8 + (nt << 9));
        bB[nt] = *(const short8v*)(b1s + lo8 + 12288 + (nt << 9));
    }

    // ---- stage x rows t0-2 .. t0+63 into As rows 0..65 (zero halo) ----
    const bool fuse_emb = (p == 2);
    if (fuse_emb) {
        if (tid < 66) {
            const int t = t0 - 2 + tid;
            int lo = 0;
            if ((unsigned)t < (unsigned)T_) {
                const float tg = P.ptgt[(b << 10) + t];
                int hi = NBINS_;
                while (lo < hi) {
                    const int mid = (lo + hi) >> 1;
                    if (P.pbins[mid] < tg) lo = mid + 1; else hi = mid;
                }
            }
            embi[tid] = lo;
        }
        __syncthreads();
    }
    for (int i = tid; i < 66 * 96; i += 512) {
        const int row = i / 96;
        const int c4  = i - row * 96;
        const int t   = t0 - 2 + row;
        uint2 pv = make_uint2(0u, 0u);
        if ((unsigned)t < (unsigned)T_) {
            float4 f = *(const float4*)(P.xf + ((size_t)(b << 10) + t) * C_ + c4 * 4);
            if (fuse_emb) {
                const float* er = P.pemb + (size_t)embi[row] * C_ + c4 * 4;
                f.x += er[0]; f.y += er[1]; f.z += er[2]; f.w += er[3];
            }
            asm("v_cvt_pk_bf16_f32 %0, %1, %2" : "=v"(pv.x) : "v"(f.x), "v"(f.y));
            asm("v_cvt_pk_bf16_f32 %0, %1, %2" : "=v"(pv.y) : "v"(f.z), "v"(f.w));
        }
        *(uint2*)&As[row * ARS + c4 * 4] = pv;
    }
    __syncthreads();

    // ========= K-loop 1: 4 m-tiles -> h1 rows j=0..63 (global t0-1+j) =====
    floatx4 acc1[12];
#pragma unroll
    for (int i = 0; i < 12; ++i) acc1[i] = (floatx4){0.f, 0.f, 0.f, 0.f};

    const unsigned short* abase = &As[ln * ARS + lq * 8];
    {
        int offA = lo8 + 2 * 12288;
        int offB = lo8 + 3 * 12288;
#pragma unroll
        for (int kc = 0; kc < 3; ++kc) {
#pragma unroll
            for (int h2 = 0; h2 < 6; ++h2) {
                const int hb = h2 * 64;
                const int r  = kc * 12 + h2 * 2;
                {   // even: consume bA
                    short8v afrag[4];
#pragma unroll
                    for (int mt = 0; mt < 4; ++mt)
                        afrag[mt] = *(const short8v*)(abase + (mt * 16 + kc) * ARS + hb);
#pragma unroll
                    for (int mt = 0; mt < 4; ++mt)
#pragma unroll
                        for (int nt = 0; nt < 3; ++nt)
                            acc1[mt * 3 + nt] = __builtin_amdgcn_mfma_f32_16x16x32_bf16(
                                afrag[mt], bA[nt], acc1[mt * 3 + nt], 0, 0, 0);
                    if (r + 2 < 36) {
#pragma unroll
                        for (int nt = 0; nt < 3; ++nt)
                            bA[nt] = *(const short8v*)(b1s + offA + (nt << 9));
                        offA += 24576;
                    }
                }
                {   // odd: consume bB
                    short8v afrag[4];
#pragma unroll
                    for (int mt = 0; mt < 4; ++mt)
                        afrag[mt] = *(const short8v*)(abase + (mt * 16 + kc) * ARS + hb + 32);
#pragma unroll
                    for (int mt = 0; mt < 4; ++mt)
#pragma unroll
                        for (int nt = 0; nt < 3; ++nt)
                            acc1[mt * 3 + nt] = __builtin_amdgcn_mfma_f32_16x16x32_bf16(
                                afrag[mt], bB[nt], acc1[mt * 3 + nt], 0, 0, 0);
                    if (r + 3 < 36) {
#pragma unroll
                        for (int nt = 0; nt < 3; ++nt)
                            bB[nt] = *(const short8v*)(b1s + offB + (nt << 9));
                        offB += 24576;
                    }
                }
            }
        }
    }
    __syncthreads();   // all x reads done; As may be overwritten

    // ---- layer1 LN: bias+relu, wave partials ----
    float c1b[3], c1g[3], c1be[3];
#pragma unroll
    for (int nt = 0; nt < 3; ++nt) {
        const int col = nb + nt * 16 + ln;
        c1b[nt]  = P.b1[p][col];
        c1g[nt]  = P.g1[p][col];
        c1be[nt] = P.be1[p][col];
    }
#pragma unroll
    for (int mt = 0; mt < 4; ++mt) {
#pragma unroll
        for (int rg = 0; rg < 4; ++rg) {
            float s = 0.f, q = 0.f;
#pragma unroll
            for (int nt = 0; nt < 3; ++nt) {
                float v = acc1[mt * 3 + nt][rg] + c1b[nt];
                v = v > 0.f ? v : 0.f;
                acc1[mt * 3 + nt][rg] = v;
                s += v; q += v * v;
            }
#pragma unroll
            for (int off = 1; off < 16; off <<= 1) {
                s += __shfl_xor(s, off, 64);
                q += __shfl_xor(q, off, 64);
            }
            if (ln == ((mt * 4 + rg) & 15)) {
                redS[wave * 64 + mt * 16 + lq * 4 + rg] = s;
                redQ[wave * 64 + mt * 16 + lq * 4 + rg] = q;
            }
        }
    }
    __syncthreads();

    // ---- LN finalize + write h1 bf16 in place into As rows 0..63 ----
#pragma unroll
    for (int mt = 0; mt < 4; ++mt) {
#pragma unroll
        for (int rg = 0; rg < 4; ++rg) {
            const int j  = mt * 16 + lq * 4 + rg;       // h1 row t0-1+j
            const int th = t0 - 1 + j;
            float s = 0.f, q = 0.f;
#pragma unroll
            for (int w = 0; w < 8; ++w) {
                s += redS[w * 64 + j];
                q += redQ[w * 64 + j];
            }
            const float m  = s * (1.f / 384.f);
            const float rs = rsqrtf(q * (1.f / 384.f) - m * m + 1e-5f);
            const bool valid = (unsigned)th < (unsigned)T_;
#pragma unroll
            for (int nt = 0; nt < 3; ++nt) {
                float v = (acc1[mt * 3 + nt][rg] - m) * rs * c1g[nt] + c1be[nt];
                if (!valid) v = 0.f;            // zero-pad halo (SAME conv)
                As[j * ARS + nb + nt * 16 + ln] = f2bf(v);
            }
        }
    }

    // ---- layer2 B prefetch (acc1 now dead) ----
    const unsigned short* b2s = rfl(P.wpk + (size_t)(3 + p) * WPK1 + wave * 1536);
#pragma unroll
    for (int nt = 0; nt < 3; ++nt) {
        bA[nt] = *(const short8v*)(b2s + lo8 + (nt << 9));
        bB[nt] = *(const short8v*)(b2s + lo8 + 12288 + (nt << 9));
    }
    __syncthreads();   // h1 writes visible to all waves

    // ========= K-loop 2: 4 m-tiles -> output rows i=0..63 (valid i<62) ====
    // i reads h1 local rows i..i+2; valid i<=61 reads <=63 (all h1);
    // i=62,63 read stale-x As rows 64,65 (finite garbage, discarded).
    floatx4 acc2[12];
#pragma unroll
    for (int i = 0; i < 12; ++i) acc2[i] = (floatx4){0.f, 0.f, 0.f, 0.f};
    {
        int offA = lo8 + 2 * 12288;
        int offB = lo8 + 3 * 12288;
#pragma unroll
        for (int kc = 0; kc < 3; ++kc) {
#pragma unroll
            for (int h2 = 0; h2 < 6; ++h2) {
                const int hb = h2 * 64;
                const int r  = kc * 12 + h2 * 2;
                {   // even: consume bA
                    short8v afrag[4];
#pragma unroll
                    for (int mt = 0; mt < 4; ++mt)
                        afrag[mt] = *(const short8v*)(abase + (mt * 16 + kc) * ARS + hb);
#pragma unroll
                    for (int mt = 0; mt < 4; ++mt)
#pragma unroll
                        for (int nt = 0; nt < 3; ++nt)
                            acc2[mt * 3 + nt] = __builtin_amdgcn_mfma_f32_16x16x32_bf16(
                                afrag[mt], bA[nt], acc2[mt * 3 + nt], 0, 0, 0);
                    if (r + 2 < 36) {
#pragma unroll
                        for (int nt = 0; nt < 3; ++nt)
                            bA[nt] = *(const short8v*)(b2s + offA + (nt << 9));
                        offA += 24576;
                    }
                }
                {   // odd: consume bB
                    short8v afrag[4];
#pragma unroll
                    for (int mt = 0; mt < 4; ++mt)
                        afrag[mt] = *(const short8v*)(abase + (mt * 16 + kc) * ARS + hb + 32);
#pragma unroll
                    for (int mt = 0; mt < 4; ++mt)
#pragma unroll
                        for (int nt = 0; nt < 3; ++nt)
                            acc2[mt * 3 + nt] = __builtin_amdgcn_mfma_f32_16x16x32_bf16(
                                afrag[mt], bB[nt], acc2[mt * 3 + nt], 0, 0, 0);
                    if (r + 3 < 36) {
#pragma unroll
                        for (int nt = 0; nt < 3; ++nt)
                            bB[nt] = *(const short8v*)(b2s + offB + (nt << 9));
                        offB += 24576;
                    }
                }
            }
        }
    }
    // redS/redQ rewrites below ordered after all finalize reads by the
    // pre-K-loop2 barrier; As not written again.

    // ---- layer2 LN partials ----
    float c2b[3], c2g[3], c2be[3], cwo[3];
#pragma unroll
    for (int nt = 0; nt < 3; ++nt) {
        const int col = nb + nt * 16 + ln;
        c2b[nt]  = P.b2[p][col];
        c2g[nt]  = P.g2[p][col];
        c2be[nt] = P.be2[p][col];
        cwo[nt]  = P.wo[p][col];
    }
#pragma unroll
    for (int mt = 0; mt < 4; ++mt) {
#pragma unroll
        for (int rg = 0; rg < 4; ++rg) {
            float s = 0.f, q = 0.f;
#pragma unroll
            for (int nt = 0; nt < 3; ++nt) {
                float v = acc2[mt * 3 + nt][rg] + c2b[nt];
                v = v > 0.f ? v : 0.f;
                acc2[mt * 3 + nt][rg] = v;
                s += v; q += v * v;
            }
#pragma unroll
            for (int off = 1; off < 16; off <<= 1) {
                s += __shfl_xor(s, off, 64);
                q += __shfl_xor(q, off, 64);
            }
            if (ln == ((mt * 4 + rg) & 15)) {
                redS[wave * 64 + mt * 16 + lq * 4 + rg] = s;
                redQ[wave * 64 + mt * 16 + lq * 4 + rg] = q;
            }
        }
    }
    __syncthreads();

    // ---- LN finalize + projection dot ----
#pragma unroll
    for (int mt = 0; mt < 4; ++mt) {
#pragma unroll
        for (int rg = 0; rg < 4; ++rg) {
            const int row = mt * 16 + lq * 4 + rg;
            float s = 0.f, q = 0.f;
#pragma unroll
            for (int w = 0; w < 8; ++w) {
                s += redS[w * 64 + row];
                q += redQ[w * 64 + row];
            }
            const float m  = s * (1.f / 384.f);
            const float rs = rsqrtf(q * (1.f / 384.f) - m * m + 1e-5f);
            float pr = 0.f;
#pragma unroll
            for (int nt = 0; nt < 3; ++nt)
                pr += ((acc2[mt * 3 + nt][rg] - m) * rs * c2g[nt] + c2be[nt]) * cwo[nt];
#pragma unroll
            for (int off = 1; off < 16; off <<= 1)
                pr += __shfl_xor(pr, off, 64);
            if (ln == ((mt * 4 + rg) & 15))
                prbuf[wave * 64 + row] = pr;
        }
    }
    __syncthreads();
    if (tid < 64) {
        const int t = t0 + tid;
        if (tid < TROWS && t < T_) {
            float s = P.bo[p][0];
#pragma unroll
            for (int w = 0; w < 8; ++w) s += prbuf[w * 64 + tid];
            P.pred[p][(b << 10) + t] = s;
        }
    }
}

// ---------------------------------------------------------------------------
// Coalesced weight pack via LDS transpose. Grid: 216 blocks = 6 wsel x 36 r.
// wpk[(r*24 + c16)*512 + lane*8 + j] = w[(r*32 + lq*8 + j)*384 + c16*16+ln]
// (c16 = 16-col fragment index 0..23 — consumed as wave*3+nt by conv)
// ---------------------------------------------------------------------------
#define WSS 388   /* LDS row stride (floats), 16B-aligned */
__global__ __launch_bounds__(256) void pack_w_kernel(
    const float* __restrict__ s0, const float* __restrict__ s1,
    const float* __restrict__ s2, const float* __restrict__ s3,
    const float* __restrict__ s4, const float* __restrict__ s5,
    unsigned short* __restrict__ dst)
{
    __shared__ float ws[32 * WSS];   // 48.5 KB
    const int blk  = blockIdx.x;
    const int wsel = blk / 36;
    const int r    = blk - wsel * 36;
    const float* src = wsel == 0 ? s0 : wsel == 1 ? s1 : wsel == 2 ? s2
                     : wsel == 3 ? s3 : wsel == 4 ? s4 : s5;
    const int tid = threadIdx.x;

    // coalesced load: 32 rows x 384 cols = 3072 float4
    const float* sb = src + (size_t)r * 32 * C_;
    for (int i4 = tid; i4 < 3072; i4 += 256) {
        const int k  = i4 / 96;
        const int n4 = i4 - k * 96;
        *(float4*)&ws[k * WSS + n4 * 4] = *(const float4*)(sb + (size_t)k * C_ + n4 * 4);
    }
    __syncthreads();

    // transpose-write: 1536 chunks of 8 bf16 (16 B), coalesced
    unsigned short* db = dst + (size_t)wsel * WPK1 + (size_t)r * 12288;
    for (int c = tid; c < 1536; c += 256) {
        const int lane = c & 63;
        const int wnt  = c >> 6;          // c16 fragment index 0..23
        const int ln   = lane & 15;
        const int lq   = lane >> 4;
        const int n    = wnt * 16 + ln;
        ushort4 o0, o1;
        unsigned short e[8];
#pragma unroll
        for (int j = 0; j < 8; ++j)
            e[j] = f2bf(ws[(lq * 8 + j) * WSS + n]);
        o0 = make_ushort4(e[0], e[1], e[2], e[3]);
        o1 = make_ushort4(e[4], e[5], e[6], e[7]);
        *(ushort4*)(db + wnt * 512 + lane * 8)     = o0;
        *(ushort4*)(db + wnt * 512 + lane * 8 + 4) = o1;
    }
}

// Fused: per-batch cumsum of duration + per-frame packed gather index
// pk = t | plo<<10 | elo<<19 (or -1 if frame >= total); mel_len.
__global__ __launch_bounds__(256) void cumsum_idx_kernel(
    const int* __restrict__ dur,
    const float* __restrict__ pbins, const float* __restrict__ ptgt,
    const float* __restrict__ ebins, const float* __restrict__ etgt,
    int* __restrict__ xidx, float* __restrict__ mel_len)
{
    __shared__ int cs[T_];
    __shared__ int part[256];
    __shared__ float pb[NBINS_], eb[NBINS_];
    const int b = blockIdx.x;
    const int tid = threadIdx.x;
    if (tid < NBINS_) { pb[tid] = pbins[tid]; eb[tid] = ebins[tid]; }
    int l[4];
    int s = 0;
#pragma unroll
    for (int i = 0; i < 4; ++i) { l[i] = dur[(b << 10) + tid * 4 + i]; s += l[i]; }
    part[tid] = s;
    __syncthreads();
    for (int off = 1; off < 256; off <<= 1) {
        int u = 0;
        if (tid >= off) u = part[tid - off];
        __syncthreads();
        part[tid] += u;
        __syncthreads();
    }
    const int incl = part[tid];
    int run = incl - s;
#pragma unroll
    for (int i = 0; i < 4; ++i) {
        run += l[i];
        cs[tid * 4 + i] = run;
    }
    if (tid == 255) mel_len[b] = (float)incl;
    __syncthreads();
    const int total = cs[T_ - 1];
    for (int f = tid; f < MAXLEN_; f += 256) {
        int pk = -1;
        if (f < total) {
            int lo = 0, hi = T_;
            while (lo < hi) {
                const int mid = (lo + hi) >> 1;
                if (cs[mid] <= f) lo = mid + 1; else hi = mid;
            }
            const int t = lo > T_ - 1 ? T_ - 1 : lo;
            const int row = (b << 10) + t;
            const float ptg = ptgt[row];
            int plo = 0, phi = NBINS_;
            while (plo < phi) {
                const int mid = (plo + phi) >> 1;
                if (pb[mid] < ptg) plo = mid + 1; else phi = mid;
            }
            const float etg = etgt[row];
            int elo = 0, ehi = NBINS_;
            while (elo < ehi) {
                const int mid = (elo + ehi) >> 1;
                if (eb[mid] < etg) elo = mid + 1; else ehi = mid;
            }
            pk = t | (plo << 10) | (elo << 19);
        }
        xidx[(b << 11) + f] = pk;
    }
}

// out[b,frame,:] = pk<0 ? 0 : x[b,t,:] + pemb[plo] + eemb[elo]  (fp32 exact)
__global__ __launch_bounds__(256) void length_reg_kernel(
    const float* __restrict__ x, const int* __restrict__ xidx,
    const float* __restrict__ pemb, const float* __restrict__ eemb,
    float* __restrict__ out)
{
    const int g    = blockIdx.x * 256 + threadIdx.x;  // B*2048*96
    const int c4   = g % 96;
    const int rest = g / 96;
    const int frame = rest & (MAXLEN_ - 1);
    const int b     = rest >> 11;
    const int pk = xidx[(b << 11) + frame];
    float4 v = make_float4(0.f, 0.f, 0.f, 0.f);
    if (pk >= 0) {
        const int t   = pk & 1023;
        const int plo = (pk >> 10) & 511;
        const int elo = (pk >> 19) & 511;
        v = *(const float4*)(x + ((size_t)(b << 10) + t) * C_ + c4 * 4);
        const float4 pe = *(const float4*)(pemb + (size_t)plo * C_ + c4 * 4);
        const float4 ee = *(const float4*)(eemb + (size_t)elo * C_ + c4 * 4);
        v.x += pe.x + ee.x; v.y += pe.y + ee.y;
        v.z += pe.z + ee.z; v.w += pe.w + ee.w;
    }
    *(float4*)(out + (size_t)g * 4) = v;
}

extern "C" void kernel_launch(void* const* d_in, const int* in_sizes, int n_in,
                              void* d_out, int out_size, void* d_ws, size_t ws_size,
                              hipStream_t stream)
{
    const float* x        = (const float*)d_in[0];
    const int*   duration = (const int*)d_in[2];
    const float* P[3][10];
    for (int p = 0; p < 3; ++p)
        for (int q = 0; q < 10; ++q)
            P[p][q] = (const float*)d_in[4 + p * 10 + q];
    const float* pitch_bins    = (const float*)d_in[34];
    const float* energy_bins   = (const float*)d_in[35];
    const float* pitch_emb     = (const float*)d_in[36];
    const float* energy_emb    = (const float*)d_in[37];
    const float* pitch_target  = (const float*)d_in[38];
    const float* energy_target = (const float*)d_in[39];

    float* out_x      = (float*)d_out;                       // (B,2048,384)
    float* out_pitch  = out_x + (size_t)B_ * MAXLEN_ * C_;
    float* out_energy = out_pitch + B_ * T_;
    float* out_logdur = out_energy + B_ * T_;
    float* out_mellen = out_logdur + B_ * T_;

    unsigned short* wpk = (unsigned short*)d_ws;             // 6*WPK1 bf16
    int* xidx = (int*)(wpk + (size_t)6 * WPK1);              // B*2048 ints

    const dim3 blk(256);
    const dim3 cblk(512);

    pack_w_kernel<<<216, blk, 0, stream>>>(
        P[0][0], P[0][4], P[1][0], P[1][4], P[2][0], P[2][4], wpk);

    CvP Pa;
    Pa.xf = x; Pa.wpk = wpk;
    for (int p = 0; p < 3; ++p) {
        Pa.b1[p]  = P[p][1];
        Pa.g1[p]  = P[p][2];
        Pa.be1[p] = P[p][3];
        Pa.b2[p]  = P[p][5];
        Pa.g2[p]  = P[p][6];
        Pa.be2[p] = P[p][7];
        Pa.wo[p]  = P[p][8];
        Pa.bo[p]  = P[p][9];
    }
    Pa.pred[0] = out_logdur; Pa.pred[1] = out_pitch; Pa.pred[2] = out_energy;
    Pa.pbins = pitch_bins; Pa.pemb = pitch_emb; Pa.ptgt = pitch_target;

    conv_fused3<<<3 * B_ * NTILE, cblk, 0, stream>>>(Pa);

    cumsum_idx_kernel<<<B_, blk, 0, stream>>>(
        duration, pitch_bins, pitch_target, energy_bins, energy_target,
        xidx, out_mellen);
    length_reg_kernel<<<24576, blk, 0, stream>>>(
        x, xidx, pitch_emb, energy_emb, out_x);
}

// Round 7
// 490.701 us; speedup vs baseline: 1.1596x; 1.1596x over previous
//
#include <hip/hip_runtime.h>

#define B_ 32
#define T_ 1024
#define C_ 384
#define MAXLEN_ 2048
#define NBINS_ 255
#define WPK1 442368          /* 36*24*512 packed bf16 elems per weight */
#define ARS 392              /* A-tile row stride in bf16 (16B-aligned) */
#define TROWS 62             /* output rows per tile */
#define NTILE 17             /* ceil(1024/62) */

typedef __attribute__((ext_vector_type(8))) short short8v;   // 8 bf16 = 4 VGPRs
typedef __attribute__((ext_vector_type(4))) float floatx4;

__device__ __forceinline__ unsigned short f2bf(float f) {
    unsigned u = __float_as_uint(f);
    u += 0x7fffu + ((u >> 16) & 1u);   // RNE
    return (unsigned short)(u >> 16);
}

// hoist a wave-uniform pointer into SGPRs (saddr+voffset addressing, saves VGPRs)
__device__ __forceinline__ const unsigned short* rfl(const unsigned short* p) {
    unsigned long long u = (unsigned long long)p;
    unsigned lo = __builtin_amdgcn_readfirstlane((unsigned)u);
    unsigned hi = __builtin_amdgcn_readfirstlane((unsigned)(u >> 32));
    return (const unsigned short*)(((unsigned long long)hi << 32) | lo);
}

struct CvP {
    const float* xf;              // fp32 x input
    const unsigned short* wpk;    // packed weights; layer1 = +p*WPK1, layer2 = +(3+p)*WPK1
    const float* b1[3];  const float* g1[3];  const float* be1[3];
    const float* b2[3];  const float* g2[3];  const float* be2[3];
    const float* wo[3];  const float* bo[3];
    float* pred[3];
    const float* pbins; const float* pemb; const float* ptgt;  // p==2 fusion
};

// ---------------------------------------------------------------------------
// R15 = R14 fused kernel with the AGPR double-allocation fixed.
// R14 post-mortem: occupancy stuck at 1 block/CU with arch=72 because the
// counter hides AGPRs: under launch_bounds(512,3) (budget ~170) the
// allocator kept acc1[12] AND acc2[12] in SEPARATE AGPR banks
// (72 arch + 96 agpr = 168 <= 170 -> 3 waves/SIMD -> 8-wave block can't
// double up). Fix: (a) ONE acc[12] array re-zeroed between K-loops
// (structural coalescing, 48 AGPR), (b) launch_bounds(512,4) -> budget 128
// forces the allocator to target <=80 arch (R14's natural arch is 72, so
// no R9-style spill expected). Target: 72-80 arch + 48 agpr <= 128 ->
// 4 waves/SIMD -> 2 blocks/CU with the fused-HBM win (WRITE ~0.4MB) intact.
// Structure (unchanged from R14): output rows [t0,t0+61], 17 tiles/batch;
// stage x rows t0-2..t0+63 (66 rows) -> K-loop1 (4 m-tiles, h1 rows
// t0-1..t0+62) -> LN -> h1 bf16 written IN PLACE into As -> K-loop2
// (4 m-tiles, top 2 rows discarded) -> prediction epilogue.
// LDS 58.2 KB; 2 blocks = 116.5 <= 160.
// ---------------------------------------------------------------------------
__global__ __launch_bounds__(512, 4) void conv_fused3(CvP P)
{
    __shared__ unsigned short As[66 * ARS];   // 51,744 B
    __shared__ float redS[8 * 64];            // 2 KB
    __shared__ float redQ[8 * 64];            // 2 KB
    __shared__ float prbuf[512];              // 2 KB
    __shared__ int embi[66];

    const int tid  = threadIdx.x;
    const int wave = tid >> 6;      // col group 0..7
    const int lane = tid & 63;
    const int lq   = lane >> 4;
    const int ln   = lane & 15;
    const int blk  = blockIdx.x;
    const int p    = blk / (B_ * NTILE);            // predictor 0..2
    const int rem  = blk - p * (B_ * NTILE);
    const int b    = rem / NTILE;
    const int k    = rem - b * NTILE;
    const int t0   = k * TROWS;                     // output rows [t0, t0+61]
    const int nb   = wave * 48;                     // 48 cols per wave

    // ---- layer1 B prefetch, steps 0 and 1 (SGPR base + voffset) ----
    const unsigned short* b1s = rfl(P.wpk + (size_t)p * WPK1 + wave * 1536);
    const int lo8 = lane * 8;
    short8v bA[3], bB[3];
#pragma unroll
    for (int nt = 0; nt < 3; ++nt) {
        bA[nt] = *(const short8v*)(b1s + lo8 + (nt << 9));
        bB[nt] = *(const short8v*)(b1s + lo8 + 12288 + (nt << 9));
    }

    // ---- stage x rows t0-2 .. t0+63 into As rows 0..65 (zero halo) ----
    const bool fuse_emb = (p == 2);
    if (fuse_emb) {
        if (tid < 66) {
            const int t = t0 - 2 + tid;
            int lo = 0;
            if ((unsigned)t < (unsigned)T_) {
                const float tg = P.ptgt[(b << 10) + t];
                int hi = NBINS_;
                while (lo < hi) {
                    const int mid = (lo + hi) >> 1;
                    if (P.pbins[mid] < tg) lo = mid + 1; else hi = mid;
                }
            }
            embi[tid] = lo;
        }
        __syncthreads();
    }
    for (int i = tid; i < 66 * 96; i += 512) {
        const int row = i / 96;
        const int c4  = i - row * 96;
        const int t   = t0 - 2 + row;
        uint2 pv = make_uint2(0u, 0u);
        if ((unsigned)t < (unsigned)T_) {
            float4 f = *(const float4*)(P.xf + ((size_t)(b << 10) + t) * C_ + c4 * 4);
            if (fuse_emb) {
                const float* er = P.pemb + (size_t)embi[row] * C_ + c4 * 4;
                f.x += er[0]; f.y += er[1]; f.z += er[2]; f.w += er[3];
            }
            asm("v_cvt_pk_bf16_f32 %0, %1, %2" : "=v"(pv.x) : "v"(f.x), "v"(f.y));
            asm("v_cvt_pk_bf16_f32 %0, %1, %2" : "=v"(pv.y) : "v"(f.z), "v"(f.w));
        }
        *(uint2*)&As[row * ARS + c4 * 4] = pv;
    }
    __syncthreads();

    // single accumulator array, reused by BOTH K-loops (48 AGPR total)
    floatx4 acc[12];
#pragma unroll
    for (int i = 0; i < 12; ++i) acc[i] = (floatx4){0.f, 0.f, 0.f, 0.f};

    const unsigned short* abase = &As[ln * ARS + lq * 8];

    // ========= K-loop 1: 4 m-tiles -> h1 rows j=0..63 (global t0-1+j) =====
    {
        int offA = lo8 + 2 * 12288;
        int offB = lo8 + 3 * 12288;
#pragma unroll
        for (int kc = 0; kc < 3; ++kc) {
#pragma unroll
            for (int h2 = 0; h2 < 6; ++h2) {
                const int hb = h2 * 64;
                const int r  = kc * 12 + h2 * 2;
                {   // even: consume bA
                    short8v afrag[4];
#pragma unroll
                    for (int mt = 0; mt < 4; ++mt)
                        afrag[mt] = *(const short8v*)(abase + (mt * 16 + kc) * ARS + hb);
#pragma unroll
                    for (int mt = 0; mt < 4; ++mt)
#pragma unroll
                        for (int nt = 0; nt < 3; ++nt)
                            acc[mt * 3 + nt] = __builtin_amdgcn_mfma_f32_16x16x32_bf16(
                                afrag[mt], bA[nt], acc[mt * 3 + nt], 0, 0, 0);
                    if (r + 2 < 36) {
#pragma unroll
                        for (int nt = 0; nt < 3; ++nt)
                            bA[nt] = *(const short8v*)(b1s + offA + (nt << 9));
                        offA += 24576;
                    }
                }
                {   // odd: consume bB
                    short8v afrag[4];
#pragma unroll
                    for (int mt = 0; mt < 4; ++mt)
                        afrag[mt] = *(const short8v*)(abase + (mt * 16 + kc) * ARS + hb + 32);
#pragma unroll
                    for (int mt = 0; mt < 4; ++mt)
#pragma unroll
                        for (int nt = 0; nt < 3; ++nt)
                            acc[mt * 3 + nt] = __builtin_amdgcn_mfma_f32_16x16x32_bf16(
                                afrag[mt], bB[nt], acc[mt * 3 + nt], 0, 0, 0);
                    if (r + 3 < 36) {
#pragma unroll
                        for (int nt = 0; nt < 3; ++nt)
                            bB[nt] = *(const short8v*)(b1s + offB + (nt << 9));
                        offB += 24576;
                    }
                }
            }
        }
    }
    __syncthreads();   // all x reads done; As may be overwritten

    // ---- layer1 LN: bias+relu, wave partials ----
    float c1b[3], c1g[3], c1be[3];
#pragma unroll
    for (int nt = 0; nt < 3; ++nt) {
        const int col = nb + nt * 16 + ln;
        c1b[nt]  = P.b1[p][col];
        c1g[nt]  = P.g1[p][col];
        c1be[nt] = P.be1[p][col];
    }
#pragma unroll
    for (int mt = 0; mt < 4; ++mt) {
#pragma unroll
        for (int rg = 0; rg < 4; ++rg) {
            float s = 0.f, q = 0.f;
#pragma unroll
            for (int nt = 0; nt < 3; ++nt) {
                float v = acc[mt * 3 + nt][rg] + c1b[nt];
                v = v > 0.f ? v : 0.f;
                acc[mt * 3 + nt][rg] = v;
                s += v; q += v * v;
            }
#pragma unroll
            for (int off = 1; off < 16; off <<= 1) {
                s += __shfl_xor(s, off, 64);
                q += __shfl_xor(q, off, 64);
            }
            if (ln == ((mt * 4 + rg) & 15)) {
                redS[wave * 64 + mt * 16 + lq * 4 + rg] = s;
                redQ[wave * 64 + mt * 16 + lq * 4 + rg] = q;
            }
        }
    }
    __syncthreads();

    // ---- LN finalize + write h1 bf16 in place into As rows 0..63 ----
#pragma unroll
    for (int mt = 0; mt < 4; ++mt) {
#pragma unroll
        for (int rg = 0; rg < 4; ++rg) {
            const int j  = mt * 16 + lq * 4 + rg;       // h1 row t0-1+j
            const int th = t0 - 1 + j;
            float s = 0.f, q = 0.f;
#pragma unroll
            for (int w = 0; w < 8; ++w) {
                s += redS[w * 64 + j];
                q += redQ[w * 64 + j];
            }
            const float m  = s * (1.f / 384.f);
            const float rs = rsqrtf(q * (1.f / 384.f) - m * m + 1e-5f);
            const bool valid = (unsigned)th < (unsigned)T_;
#pragma unroll
            for (int nt = 0; nt < 3; ++nt) {
                float v = (acc[mt * 3 + nt][rg] - m) * rs * c1g[nt] + c1be[nt];
                if (!valid) v = 0.f;            // zero-pad halo (SAME conv)
                As[j * ARS + nb + nt * 16 + ln] = f2bf(v);
            }
        }
    }

    // ---- layer2 B prefetch (layer1 acc values now dead) ----
    const unsigned short* b2s = rfl(P.wpk + (size_t)(3 + p) * WPK1 + wave * 1536);
#pragma unroll
    for (int nt = 0; nt < 3; ++nt) {
        bA[nt] = *(const short8v*)(b2s + lo8 + (nt << 9));
        bB[nt] = *(const short8v*)(b2s + lo8 + 12288 + (nt << 9));
    }
    __syncthreads();   // h1 writes visible to all waves

    // re-zero the SAME accumulator array for layer2
#pragma unroll
    for (int i = 0; i < 12; ++i) acc[i] = (floatx4){0.f, 0.f, 0.f, 0.f};

    // ========= K-loop 2: 4 m-tiles -> output rows i=0..63 (valid i<62) ====
    // i reads h1 local rows i..i+2; valid i<=61 reads <=63 (all h1);
    // i=62,63 read stale-x As rows 64,65 (finite garbage, discarded).
    {
        int offA = lo8 + 2 * 12288;
        int offB = lo8 + 3 * 12288;
#pragma unroll
        for (int kc = 0; kc < 3; ++kc) {
#pragma unroll
            for (int h2 = 0; h2 < 6; ++h2) {
                const int hb = h2 * 64;
                const int r  = kc * 12 + h2 * 2;
                {   // even: consume bA
                    short8v afrag[4];
#pragma unroll
                    for (int mt = 0; mt < 4; ++mt)
                        afrag[mt] = *(const short8v*)(abase + (mt * 16 + kc) * ARS + hb);
#pragma unroll
                    for (int mt = 0; mt < 4; ++mt)
#pragma unroll
                        for (int nt = 0; nt < 3; ++nt)
                            acc[mt * 3 + nt] = __builtin_amdgcn_mfma_f32_16x16x32_bf16(
                                afrag[mt], bA[nt], acc[mt * 3 + nt], 0, 0, 0);
                    if (r + 2 < 36) {
#pragma unroll
                        for (int nt = 0; nt < 3; ++nt)
                            bA[nt] = *(const short8v*)(b2s + offA + (nt << 9));
                        offA += 24576;
                    }
                }
                {   // odd: consume bB
                    short8v afrag[4];
#pragma unroll
                    for (int mt = 0; mt < 4; ++mt)
                        afrag[mt] = *(const short8v*)(abase + (mt * 16 + kc) * ARS + hb + 32);
#pragma unroll
                    for (int mt = 0; mt < 4; ++mt)
#pragma unroll
                        for (int nt = 0; nt < 3; ++nt)
                            acc[mt * 3 + nt] = __builtin_amdgcn_mfma_f32_16x16x32_bf16(
                                afrag[mt], bB[nt], acc[mt * 3 + nt], 0, 0, 0);
                    if (r + 3 < 36) {
#pragma unroll
                        for (int nt = 0; nt < 3; ++nt)
                            bB[nt] = *(const short8v*)(b2s + offB + (nt << 9));
                        offB += 24576;
                    }
                }
            }
        }
    }
    // redS/redQ rewrites below ordered after all finalize reads by the
    // pre-K-loop2 barrier; As not written again.

    // ---- layer2 LN partials ----
    float c2b[3], c2g[3], c2be[3], cwo[3];
#pragma unroll
    for (int nt = 0; nt < 3; ++nt) {
        const int col = nb + nt * 16 + ln;
        c2b[nt]  = P.b2[p][col];
        c2g[nt]  = P.g2[p][col];
        c2be[nt] = P.be2[p][col];
        cwo[nt]  = P.wo[p][col];
    }
#pragma unroll
    for (int mt = 0; mt < 4; ++mt) {
#pragma unroll
        for (int rg = 0; rg < 4; ++rg) {
            float s = 0.f, q = 0.f;
#pragma unroll
            for (int nt = 0; nt < 3; ++nt) {
                float v = acc[mt * 3 + nt][rg] + c2b[nt];
                v = v > 0.f ? v : 0.f;
                acc[mt * 3 + nt][rg] = v;
                s += v; q += v * v;
            }
#pragma unroll
            for (int off = 1; off < 16; off <<= 1) {
                s += __shfl_xor(s, off, 64);
                q += __shfl_xor(q, off, 64);
            }
            if (ln == ((mt * 4 + rg) & 15)) {
                redS[wave * 64 + mt * 16 + lq * 4 + rg] = s;
                redQ[wave * 64 + mt * 16 + lq * 4 + rg] = q;
            }
        }
    }
    __syncthreads();

    // ---- LN finalize + projection dot ----
#pragma unroll
    for (int mt = 0; mt < 4; ++mt) {
#pragma unroll
        for (int rg = 0; rg < 4; ++rg) {
            const int row = mt * 16 + lq * 4 + rg;
            float s = 0.f, q = 0.f;
#pragma unroll
            for (int w = 0; w < 8; ++w) {
                s += redS[w * 64 + row];
                q += redQ[w * 64 + row];
            }
            const float m  = s * (1.f / 384.f);
            const float rs = rsqrtf(q * (1.f / 384.f) - m * m + 1e-5f);
            float pr = 0.f;
#pragma unroll
            for (int nt = 0; nt < 3; ++nt)
                pr += ((acc[mt * 3 + nt][rg] - m) * rs * c2g[nt] + c2be[nt]) * cwo[nt];
#pragma unroll
            for (int off = 1; off < 16; off <<= 1)
                pr += __shfl_xor(pr, off, 64);
            if (ln == ((mt * 4 + rg) & 15))
                prbuf[wave * 64 + row] = pr;
        }
    }
    __syncthreads();
    if (tid < 64) {
        const int t = t0 + tid;
        if (tid < TROWS && t < T_) {
            float s = P.bo[p][0];
#pragma unroll
            for (int w = 0; w < 8; ++w) s += prbuf[w * 64 + tid];
            P.pred[p][(b << 10) + t] = s;
        }
    }
}

// ---------------------------------------------------------------------------
// Coalesced weight pack via LDS transpose. Grid: 216 blocks = 6 wsel x 36 r.
// wpk[(r*24 + c16)*512 + lane*8 + j] = w[(r*32 + lq*8 + j)*384 + c16*16+ln]
// (c16 = 16-col fragment index 0..23 — consumed as wave*3+nt by conv)
// ---------------------------------------------------------------------------
#define WSS 388   /* LDS row stride (floats), 16B-aligned */
__global__ __launch_bounds__(256) void pack_w_kernel(
    const float* __restrict__ s0, const float* __restrict__ s1,
    const float* __restrict__ s2, const float* __restrict__ s3,
    const float* __restrict__ s4, const float* __restrict__ s5,
    unsigned short* __restrict__ dst)
{
    __shared__ float ws[32 * WSS];   // 48.5 KB
    const int blk  = blockIdx.x;
    const int wsel = blk / 36;
    const int r    = blk - wsel * 36;
    const float* src = wsel == 0 ? s0 : wsel == 1 ? s1 : wsel == 2 ? s2
                     : wsel == 3 ? s3 : wsel == 4 ? s4 : s5;
    const int tid = threadIdx.x;

    // coalesced load: 32 rows x 384 cols = 3072 float4
    const float* sb = src + (size_t)r * 32 * C_;
    for (int i4 = tid; i4 < 3072; i4 += 256) {
        const int k  = i4 / 96;
        const int n4 = i4 - k * 96;
        *(float4*)&ws[k * WSS + n4 * 4] = *(const float4*)(sb + (size_t)k * C_ + n4 * 4);
    }
    __syncthreads();

    // transpose-write: 1536 chunks of 8 bf16 (16 B), coalesced
    unsigned short* db = dst + (size_t)wsel * WPK1 + (size_t)r * 12288;
    for (int c = tid; c < 1536; c += 256) {
        const int lane = c & 63;
        const int wnt  = c >> 6;          // c16 fragment index 0..23
        const int ln   = lane & 15;
        const int lq   = lane >> 4;
        const int n    = wnt * 16 + ln;
        ushort4 o0, o1;
        unsigned short e[8];
#pragma unroll
        for (int j = 0; j < 8; ++j)
            e[j] = f2bf(ws[(lq * 8 + j) * WSS + n]);
        o0 = make_ushort4(e[0], e[1], e[2], e[3]);
        o1 = make_ushort4(e[4], e[5], e[6], e[7]);
        *(ushort4*)(db + wnt * 512 + lane * 8)     = o0;
        *(ushort4*)(db + wnt * 512 + lane * 8 + 4) = o1;
    }
}

// Fused: per-batch cumsum of duration + per-frame packed gather index
// pk = t | plo<<10 | elo<<19 (or -1 if frame >= total); mel_len.
__global__ __launch_bounds__(256) void cumsum_idx_kernel(
    const int* __restrict__ dur,
    const float* __restrict__ pbins, const float* __restrict__ ptgt,
    const float* __restrict__ ebins, const float* __restrict__ etgt,
    int* __restrict__ xidx, float* __restrict__ mel_len)
{
    __shared__ int cs[T_];
    __shared__ int part[256];
    __shared__ float pb[NBINS_], eb[NBINS_];
    const int b = blockIdx.x;
    const int tid = threadIdx.x;
    if (tid < NBINS_) { pb[tid] = pbins[tid]; eb[tid] = ebins[tid]; }
    int l[4];
    int s = 0;
#pragma unroll
    for (int i = 0; i < 4; ++i) { l[i] = dur[(b << 10) + tid * 4 + i]; s += l[i]; }
    part[tid] = s;
    __syncthreads();
    for (int off = 1; off < 256; off <<= 1) {
        int u = 0;
        if (tid >= off) u = part[tid - off];
        __syncthreads();
        part[tid] += u;
        __syncthreads();
    }
    const int incl = part[tid];
    int run = incl - s;
#pragma unroll
    for (int i = 0; i < 4; ++i) {
        run += l[i];
        cs[tid * 4 + i] = run;
    }
    if (tid == 255) mel_len[b] = (float)incl;
    __syncthreads();
    const int total = cs[T_ - 1];
    for (int f = tid; f < MAXLEN_; f += 256) {
        int pk = -1;
        if (f < total) {
            int lo = 0, hi = T_;
            while (lo < hi) {
                const int mid = (lo + hi) >> 1;
                if (cs[mid] <= f) lo = mid + 1; else hi = mid;
            }
            const int t = lo > T_ - 1 ? T_ - 1 : lo;
            const int row = (b << 10) + t;
            const float ptg = ptgt[row];
            int plo = 0, phi = NBINS_;
            while (plo < phi) {
                const int mid = (plo + phi) >> 1;
                if (pb[mid] < ptg) plo = mid + 1; else phi = mid;
            }
            const float etg = etgt[row];
            int elo = 0, ehi = NBINS_;
            while (elo < ehi) {
                const int mid = (elo + ehi) >> 1;
                if (eb[mid] < etg) elo = mid + 1; else ehi = mid;
            }
            pk = t | (plo << 10) | (elo << 19);
        }
        xidx[(b << 11) + f] = pk;
    }
}

// out[b,frame,:] = pk<0 ? 0 : x[b,t,:] + pemb[plo] + eemb[elo]  (fp32 exact)
__global__ __launch_bounds__(256) void length_reg_kernel(
    const float* __restrict__ x, const int* __restrict__ xidx,
    const float* __restrict__ pemb, const float* __restrict__ eemb,
    float* __restrict__ out)
{
    const int g    = blockIdx.x * 256 + threadIdx.x;  // B*2048*96
    const int c4   = g % 96;
    const int rest = g / 96;
    const int frame = rest & (MAXLEN_ - 1);
    const int b     = rest >> 11;
    const int pk = xidx[(b << 11) + frame];
    float4 v = make_float4(0.f, 0.f, 0.f, 0.f);
    if (pk >= 0) {
        const int t   = pk & 1023;
        const int plo = (pk >> 10) & 511;
        const int elo = (pk >> 19) & 511;
        v = *(const float4*)(x + ((size_t)(b << 10) + t) * C_ + c4 * 4);
        const float4 pe = *(const float4*)(pemb + (size_t)plo * C_ + c4 * 4);
        const float4 ee = *(const float4*)(eemb + (size_t)elo * C_ + c4 * 4);
        v.x += pe.x + ee.x; v.y += pe.y + ee.y;
        v.z += pe.z + ee.z; v.w += pe.w + ee.w;
    }
    *(float4*)(out + (size_t)g * 4) = v;
}

extern "C" void kernel_launch(void* const* d_in, const int* in_sizes, int n_in,
                              void* d_out, int out_size, void* d_ws, size_t ws_size,
                              hipStream_t stream)
{
    const float* x        = (const float*)d_in[0];
    const int*   duration = (const int*)d_in[2];
    const float* P[3][10];
    for (int p = 0; p < 3; ++p)
        for (int q = 0; q < 10; ++q)
            P[p][q] = (const float*)d_in[4 + p * 10 + q];
    const float* pitch_bins    = (const float*)d_in[34];
    const float* energy_bins   = (const float*)d_in[35];
    const float* pitch_emb     = (const float*)d_in[36];
    const float* energy_emb    = (const float*)d_in[37];
    const float* pitch_target  = (const float*)d_in[38];
    const float* energy_target = (const float*)d_in[39];

    float* out_x      = (float*)d_out;                       // (B,2048,384)
    float* out_pitch  = out_x + (size_t)B_ * MAXLEN_ * C_;
    float* out_energy = out_pitch + B_ * T_;
    float* out_logdur = out_energy + B_ * T_;
    float* out_mellen = out_logdur + B_ * T_;

    unsigned short* wpk = (unsigned short*)d_ws;             // 6*WPK1 bf16
    int* xidx = (int*)(wpk + (size_t)6 * WPK1);              // B*2048 ints

    const dim3 blk(256);
    const dim3 cblk(512);

    pack_w_kernel<<<216, blk, 0, stream>>>(
        P[0][0], P[0][4], P[1][0], P[1][4], P[2][0], P[2][4], wpk);

    CvP Pa;
    Pa.xf = x; Pa.wpk = wpk;
    for (int p = 0; p < 3; ++p) {
        Pa.b1[p]  = P[p][1];
        Pa.g1[p]  = P[p][2];
        Pa.be1[p] = P[p][3];
        Pa.b2[p]  = P[p][5];
        Pa.g2[p]  = P[p][6];
        Pa.be2[p] = P[p][7];
        Pa.wo[p]  = P[p][8];
        Pa.bo[p]  = P[p][9];
    }
    Pa.pred[0] = out_logdur; Pa.pred[1] = out_pitch; Pa.pred[2] = out_energy;
    Pa.pbins = pitch_bins; Pa.pemb = pitch_emb; Pa.ptgt = pitch_target;

    conv_fused3<<<3 * B_ * NTILE, cblk, 0, stream>>>(Pa);

    cumsum_idx_kernel<<<B_, blk, 0, stream>>>(
        duration, pitch_bins, pitch_target, energy_bins, energy_target,
        xidx, out_mellen);
    length_reg_kernel<<<24576, blk, 0, stream>>>(
        x, xidx, pitch_emb, energy_emb, out_x);
}

// Round 8
// 442.743 us; speedup vs baseline: 1.2852x; 1.1083x over previous
//
#include <hip/hip_runtime.h>

#define B_ 32
#define T_ 1024
#define C_ 384
#define MAXLEN_ 2048
#define NBINS_ 255
#define WPK1 442368          /* 36*24*512 packed bf16 elems per weight */
#define ARS 392              /* A-tile row stride in bf16 (16B-aligned) */
#define TROWS 62             /* output rows per tile */
#define NTILE 17             /* ceil(1024/62) */

typedef __attribute__((ext_vector_type(8))) short short8v;   // 8 bf16 = 4 VGPRs
typedef __attribute__((ext_vector_type(4))) float floatx4;

__device__ __forceinline__ unsigned short f2bf(float f) {
    unsigned u = __float_as_uint(f);
    u += 0x7fffu + ((u >> 16) & 1u);   // RNE
    return (unsigned short)(u >> 16);
}

// hoist a wave-uniform pointer into SGPRs (saddr+voffset addressing, saves VGPRs)
__device__ __forceinline__ const unsigned short* rfl(const unsigned short* p) {
    unsigned long long u = (unsigned long long)p;
    unsigned lo = __builtin_amdgcn_readfirstlane((unsigned)u);
    unsigned hi = __builtin_amdgcn_readfirstlane((unsigned)(u >> 32));
    return (const unsigned short*)(((unsigned long long)hi << 32) | lo);
}

struct CvP {
    const float* xf;              // fp32 x input
    const unsigned short* wpk;    // packed weights; layer1 = +p*WPK1, layer2 = +(3+p)*WPK1
    const float* b1[3];  const float* g1[3];  const float* be1[3];
    const float* b2[3];  const float* g2[3];  const float* be2[3];
    const float* wo[3];  const float* bo[3];
    float* pred[3];
    const float* pbins; const float* pemb; const float* ptgt;  // p==2 fusion
};

// ---------------------------------------------------------------------------
// R16 = R15 (fused, single acc[12], (512,4), 2 blocks/CU @ 38% occ, 276us)
// with three cuts aimed at the non-MFMA 2/3 of the round:
//  (a) mrs-precompute: cross-wave LN reduction done ONCE per row by 64
//      threads into mrsM/mrsR; finalize reads 2 broadcast values per
//      (mt,rg) instead of 16 (256 -> 32 ds_read_b32 per thread, x2 epilogues)
//  (b) defer c1g/c1be + c2g/c2be/cwo loads past the shfl-heavy partials
//      phases (R15 spilled ~48B/thread at the 128-reg cap; WRITE 39.6MB)
//  (c) s_setprio(1) around MFMA clusters (2 resident blocks run
//      phase-shifted -> scheduler prefers the MFMA-ready block), and
//      incremental row/c4 staging indexing (no per-iter div by 96).
// Structure unchanged: output rows [t0,t0+61], 17 tiles/batch, grid 1632;
// stage x 66 rows -> K1 (4 m-tiles) -> LN1 -> h1 in place -> K2 -> pred.
// ---------------------------------------------------------------------------
__global__ __launch_bounds__(512, 4) void conv_fused3(CvP P)
{
    __shared__ unsigned short As[66 * ARS];   // 51,744 B
    __shared__ float redS[8 * 64];            // 2 KB
    __shared__ float redQ[8 * 64];            // 2 KB
    __shared__ float prbuf[512];              // 2 KB
    __shared__ float mrsM[64], mrsR[64];      // per-row mean / rstd
    __shared__ int embi[66];

    const int tid  = threadIdx.x;
    const int wave = tid >> 6;      // col group 0..7
    const int lane = tid & 63;
    const int lq   = lane >> 4;
    const int ln   = lane & 15;
    const int blk  = blockIdx.x;
    const int p    = blk / (B_ * NTILE);            // predictor 0..2
    const int rem  = blk - p * (B_ * NTILE);
    const int b    = rem / NTILE;
    const int k    = rem - b * NTILE;
    const int t0   = k * TROWS;                     // output rows [t0, t0+61]
    const int nb   = wave * 48;                     // 48 cols per wave

    // ---- layer1 B prefetch, steps 0 and 1 (SGPR base + voffset) ----
    const unsigned short* b1s = rfl(P.wpk + (size_t)p * WPK1 + wave * 1536);
    const int lo8 = lane * 8;
    short8v bA[3], bB[3];
#pragma unroll
    for (int nt = 0; nt < 3; ++nt) {
        bA[nt] = *(const short8v*)(b1s + lo8 + (nt << 9));
        bB[nt] = *(const short8v*)(b1s + lo8 + 12288 + (nt << 9));
    }

    // ---- stage x rows t0-2 .. t0+63 into As rows 0..65 (zero halo) ----
    const bool fuse_emb = (p == 2);
    if (fuse_emb) {
        if (tid < 66) {
            const int t = t0 - 2 + tid;
            int lo = 0;
            if ((unsigned)t < (unsigned)T_) {
                const float tg = P.ptgt[(b << 10) + t];
                int hi = NBINS_;
                while (lo < hi) {
                    const int mid = (lo + hi) >> 1;
                    if (P.pbins[mid] < tg) lo = mid + 1; else hi = mid;
                }
            }
            embi[tid] = lo;
        }
        __syncthreads();
    }
    {
        int row = tid / 96;
        int c4  = tid - row * 96;
        while (row < 66) {
            const int t = t0 - 2 + row;
            uint2 pv = make_uint2(0u, 0u);
            if ((unsigned)t < (unsigned)T_) {
                float4 f = *(const float4*)(P.xf + ((size_t)(b << 10) + t) * C_ + c4 * 4);
                if (fuse_emb) {
                    const float* er = P.pemb + (size_t)embi[row] * C_ + c4 * 4;
                    f.x += er[0]; f.y += er[1]; f.z += er[2]; f.w += er[3];
                }
                asm("v_cvt_pk_bf16_f32 %0, %1, %2" : "=v"(pv.x) : "v"(f.x), "v"(f.y));
                asm("v_cvt_pk_bf16_f32 %0, %1, %2" : "=v"(pv.y) : "v"(f.z), "v"(f.w));
            }
            *(uint2*)&As[row * ARS + c4 * 4] = pv;
            c4 += 32; row += 5;
            if (c4 >= 96) { c4 -= 96; row += 1; }   // +512 linear
        }
    }
    __syncthreads();

    // single accumulator array, reused by BOTH K-loops (48 AGPR total)
    floatx4 acc[12];
#pragma unroll
    for (int i = 0; i < 12; ++i) acc[i] = (floatx4){0.f, 0.f, 0.f, 0.f};

    const unsigned short* abase = &As[ln * ARS + lq * 8];

    // ========= K-loop 1: 4 m-tiles -> h1 rows j=0..63 (global t0-1+j) =====
    {
        int offA = lo8 + 2 * 12288;
        int offB = lo8 + 3 * 12288;
#pragma unroll
        for (int kc = 0; kc < 3; ++kc) {
#pragma unroll
            for (int h2 = 0; h2 < 6; ++h2) {
                const int hb = h2 * 64;
                const int r  = kc * 12 + h2 * 2;
                {   // even: consume bA
                    short8v afrag[4];
#pragma unroll
                    for (int mt = 0; mt < 4; ++mt)
                        afrag[mt] = *(const short8v*)(abase + (mt * 16 + kc) * ARS + hb);
                    __builtin_amdgcn_s_setprio(1);
#pragma unroll
                    for (int mt = 0; mt < 4; ++mt)
#pragma unroll
                        for (int nt = 0; nt < 3; ++nt)
                            acc[mt * 3 + nt] = __builtin_amdgcn_mfma_f32_16x16x32_bf16(
                                afrag[mt], bA[nt], acc[mt * 3 + nt], 0, 0, 0);
                    __builtin_amdgcn_s_setprio(0);
                    if (r + 2 < 36) {
#pragma unroll
                        for (int nt = 0; nt < 3; ++nt)
                            bA[nt] = *(const short8v*)(b1s + offA + (nt << 9));
                        offA += 24576;
                    }
                }
                {   // odd: consume bB
                    short8v afrag[4];
#pragma unroll
                    for (int mt = 0; mt < 4; ++mt)
                        afrag[mt] = *(const short8v*)(abase + (mt * 16 + kc) * ARS + hb + 32);
                    __builtin_amdgcn_s_setprio(1);
#pragma unroll
                    for (int mt = 0; mt < 4; ++mt)
#pragma unroll
                        for (int nt = 0; nt < 3; ++nt)
                            acc[mt * 3 + nt] = __builtin_amdgcn_mfma_f32_16x16x32_bf16(
                                afrag[mt], bB[nt], acc[mt * 3 + nt], 0, 0, 0);
                    __builtin_amdgcn_s_setprio(0);
                    if (r + 3 < 36) {
#pragma unroll
                        for (int nt = 0; nt < 3; ++nt)
                            bB[nt] = *(const short8v*)(b1s + offB + (nt << 9));
                        offB += 24576;
                    }
                }
            }
        }
    }
    __syncthreads();   // all x reads done; As may be overwritten

    // ---- layer1 LN partials: bias+relu, per-wave shfl reduce ----
    {
        float c1b[3];
#pragma unroll
        for (int nt = 0; nt < 3; ++nt)
            c1b[nt] = P.b1[p][nb + nt * 16 + ln];
#pragma unroll
        for (int mt = 0; mt < 4; ++mt) {
#pragma unroll
            for (int rg = 0; rg < 4; ++rg) {
                float s = 0.f, q = 0.f;
#pragma unroll
                for (int nt = 0; nt < 3; ++nt) {
                    float v = acc[mt * 3 + nt][rg] + c1b[nt];
                    v = v > 0.f ? v : 0.f;
                    acc[mt * 3 + nt][rg] = v;
                    s += v; q += v * v;
                }
#pragma unroll
                for (int off = 1; off < 16; off <<= 1) {
                    s += __shfl_xor(s, off, 64);
                    q += __shfl_xor(q, off, 64);
                }
                if (ln == ((mt * 4 + rg) & 15)) {
                    redS[wave * 64 + mt * 16 + lq * 4 + rg] = s;
                    redQ[wave * 64 + mt * 16 + lq * 4 + rg] = q;
                }
            }
        }
    }
    __syncthreads();

    // ---- cross-wave reduce ONCE per row (64 threads) ----
    if (tid < 64) {
        float s = 0.f, q = 0.f;
#pragma unroll
        for (int w = 0; w < 8; ++w) {
            s += redS[w * 64 + tid];
            q += redQ[w * 64 + tid];
        }
        const float m = s * (1.f / 384.f);
        mrsM[tid] = m;
        mrsR[tid] = rsqrtf(q * (1.f / 384.f) - m * m + 1e-5f);
    }
    __syncthreads();

    // ---- LN1 finalize + write h1 bf16 in place into As rows 0..63 ----
    {
        float c1g[3], c1be[3];
#pragma unroll
        for (int nt = 0; nt < 3; ++nt) {
            c1g[nt]  = P.g1[p][nb + nt * 16 + ln];
            c1be[nt] = P.be1[p][nb + nt * 16 + ln];
        }
#pragma unroll
        for (int mt = 0; mt < 4; ++mt) {
#pragma unroll
            for (int rg = 0; rg < 4; ++rg) {
                const int j  = mt * 16 + lq * 4 + rg;       // h1 row t0-1+j
                const int th = t0 - 1 + j;
                const float m  = mrsM[j];
                const float rs = mrsR[j];
                const bool valid = (unsigned)th < (unsigned)T_;
#pragma unroll
                for (int nt = 0; nt < 3; ++nt) {
                    float v = (acc[mt * 3 + nt][rg] - m) * rs * c1g[nt] + c1be[nt];
                    if (!valid) v = 0.f;            // zero-pad halo (SAME conv)
                    As[j * ARS + nb + nt * 16 + ln] = f2bf(v);
                }
            }
        }
    }

    // ---- layer2 B prefetch (layer1 acc values now dead) ----
    const unsigned short* b2s = rfl(P.wpk + (size_t)(3 + p) * WPK1 + wave * 1536);
#pragma unroll
    for (int nt = 0; nt < 3; ++nt) {
        bA[nt] = *(const short8v*)(b2s + lo8 + (nt << 9));
        bB[nt] = *(const short8v*)(b2s + lo8 + 12288 + (nt << 9));
    }
    __syncthreads();   // h1 writes visible to all waves

    // re-zero the SAME accumulator array for layer2
#pragma unroll
    for (int i = 0; i < 12; ++i) acc[i] = (floatx4){0.f, 0.f, 0.f, 0.f};

    // ========= K-loop 2: 4 m-tiles -> output rows i=0..63 (valid i<62) ====
    // i=62,63 read stale-x As rows 64,65 (finite garbage, discarded).
    {
        int offA = lo8 + 2 * 12288;
        int offB = lo8 + 3 * 12288;
#pragma unroll
        for (int kc = 0; kc < 3; ++kc) {
#pragma unroll
            for (int h2 = 0; h2 < 6; ++h2) {
                const int hb = h2 * 64;
                const int r  = kc * 12 + h2 * 2;
                {   // even: consume bA
                    short8v afrag[4];
#pragma unroll
                    for (int mt = 0; mt < 4; ++mt)
                        afrag[mt] = *(const short8v*)(abase + (mt * 16 + kc) * ARS + hb);
                    __builtin_amdgcn_s_setprio(1);
#pragma unroll
                    for (int mt = 0; mt < 4; ++mt)
#pragma unroll
                        for (int nt = 0; nt < 3; ++nt)
                            acc[mt * 3 + nt] = __builtin_amdgcn_mfma_f32_16x16x32_bf16(
                                afrag[mt], bA[nt], acc[mt * 3 + nt], 0, 0, 0);
                    __builtin_amdgcn_s_setprio(0);
                    if (r + 2 < 36) {
#pragma unroll
                        for (int nt = 0; nt < 3; ++nt)
                            bA[nt] = *(const short8v*)(b2s + offA + (nt << 9));
                        offA += 24576;
                    }
                }
                {   // odd: consume bB
                    short8v afrag[4];
#pragma unroll
                    for (int mt = 0; mt < 4; ++mt)
                        afrag[mt] = *(const short8v*)(abase + (mt * 16 + kc) * ARS + hb + 32);
                    __builtin_amdgcn_s_setprio(1);
#pragma unroll
                    for (int mt = 0; mt < 4; ++mt)
#pragma unroll
                        for (int nt = 0; nt < 3; ++nt)
                            acc[mt * 3 + nt] = __builtin_amdgcn_mfma_f32_16x16x32_bf16(
                                afrag[mt], bB[nt], acc[mt * 3 + nt], 0, 0, 0);
                    __builtin_amdgcn_s_setprio(0);
                    if (r + 3 < 36) {
#pragma unroll
                        for (int nt = 0; nt < 3; ++nt)
                            bB[nt] = *(const short8v*)(b2s + offB + (nt << 9));
                        offB += 24576;
                    }
                }
            }
        }
    }
    // redS/redQ/mrs rewrites below are ordered after all epilogue-1 reads
    // by the pre-K-loop2 barrier; As not written again.

    // ---- layer2 LN partials ----
    {
        float c2b[3];
#pragma unroll
        for (int nt = 0; nt < 3; ++nt)
            c2b[nt] = P.b2[p][nb + nt * 16 + ln];
#pragma unroll
        for (int mt = 0; mt < 4; ++mt) {
#pragma unroll
            for (int rg = 0; rg < 4; ++rg) {
                float s = 0.f, q = 0.f;
#pragma unroll
                for (int nt = 0; nt < 3; ++nt) {
                    float v = acc[mt * 3 + nt][rg] + c2b[nt];
                    v = v > 0.f ? v : 0.f;
                    acc[mt * 3 + nt][rg] = v;
                    s += v; q += v * v;
                }
#pragma unroll
                for (int off = 1; off < 16; off <<= 1) {
                    s += __shfl_xor(s, off, 64);
                    q += __shfl_xor(q, off, 64);
                }
                if (ln == ((mt * 4 + rg) & 15)) {
                    redS[wave * 64 + mt * 16 + lq * 4 + rg] = s;
                    redQ[wave * 64 + mt * 16 + lq * 4 + rg] = q;
                }
            }
        }
    }
    __syncthreads();

    if (tid < 64) {
        float s = 0.f, q = 0.f;
#pragma unroll
        for (int w = 0; w < 8; ++w) {
            s += redS[w * 64 + tid];
            q += redQ[w * 64 + tid];
        }
        const float m = s * (1.f / 384.f);
        mrsM[tid] = m;
        mrsR[tid] = rsqrtf(q * (1.f / 384.f) - m * m + 1e-5f);
    }
    __syncthreads();

    // ---- LN2 finalize + projection dot ----
    {
        float c2g[3], c2be[3], cwo[3];
#pragma unroll
        for (int nt = 0; nt < 3; ++nt) {
            c2g[nt]  = P.g2[p][nb + nt * 16 + ln];
            c2be[nt] = P.be2[p][nb + nt * 16 + ln];
            cwo[nt]  = P.wo[p][nb + nt * 16 + ln];
        }
#pragma unroll
        for (int mt = 0; mt < 4; ++mt) {
#pragma unroll
            for (int rg = 0; rg < 4; ++rg) {
                const int row = mt * 16 + lq * 4 + rg;
                const float m  = mrsM[row];
                const float rs = mrsR[row];
                float pr = 0.f;
#pragma unroll
                for (int nt = 0; nt < 3; ++nt)
                    pr += ((acc[mt * 3 + nt][rg] - m) * rs * c2g[nt] + c2be[nt]) * cwo[nt];
#pragma unroll
                for (int off = 1; off < 16; off <<= 1)
                    pr += __shfl_xor(pr, off, 64);
                if (ln == ((mt * 4 + rg) & 15))
                    prbuf[wave * 64 + row] = pr;
            }
        }
    }
    __syncthreads();
    if (tid < 64) {
        const int t = t0 + tid;
        if (tid < TROWS && t < T_) {
            float s = P.bo[p][0];
#pragma unroll
            for (int w = 0; w < 8; ++w) s += prbuf[w * 64 + tid];
            P.pred[p][(b << 10) + t] = s;
        }
    }
}

// ---------------------------------------------------------------------------
// Coalesced weight pack via LDS transpose. Grid: 216 blocks = 6 wsel x 36 r.
// wpk[(r*24 + c16)*512 + lane*8 + j] = w[(r*32 + lq*8 + j)*384 + c16*16+ln]
// (c16 = 16-col fragment index 0..23 — consumed as wave*3+nt by conv)
// ---------------------------------------------------------------------------
#define WSS 388   /* LDS row stride (floats), 16B-aligned */
__global__ __launch_bounds__(256) void pack_w_kernel(
    const float* __restrict__ s0, const float* __restrict__ s1,
    const float* __restrict__ s2, const float* __restrict__ s3,
    const float* __restrict__ s4, const float* __restrict__ s5,
    unsigned short* __restrict__ dst)
{
    __shared__ float ws[32 * WSS];   // 48.5 KB
    const int blk  = blockIdx.x;
    const int wsel = blk / 36;
    const int r    = blk - wsel * 36;
    const float* src = wsel == 0 ? s0 : wsel == 1 ? s1 : wsel == 2 ? s2
                     : wsel == 3 ? s3 : wsel == 4 ? s4 : s5;
    const int tid = threadIdx.x;

    // coalesced load: 32 rows x 384 cols = 3072 float4
    const float* sb = src + (size_t)r * 32 * C_;
    for (int i4 = tid; i4 < 3072; i4 += 256) {
        const int k  = i4 / 96;
        const int n4 = i4 - k * 96;
        *(float4*)&ws[k * WSS + n4 * 4] = *(const float4*)(sb + (size_t)k * C_ + n4 * 4);
    }
    __syncthreads();

    // transpose-write: 1536 chunks of 8 bf16 (16 B), coalesced
    unsigned short* db = dst + (size_t)wsel * WPK1 + (size_t)r * 12288;
    for (int c = tid; c < 1536; c += 256) {
        const int lane = c & 63;
        const int wnt  = c >> 6;          // c16 fragment index 0..23
        const int ln   = lane & 15;
        const int lq   = lane >> 4;
        const int n    = wnt * 16 + ln;
        ushort4 o0, o1;
        unsigned short e[8];
#pragma unroll
        for (int j = 0; j < 8; ++j)
            e[j] = f2bf(ws[(lq * 8 + j) * WSS + n]);
        o0 = make_ushort4(e[0], e[1], e[2], e[3]);
        o1 = make_ushort4(e[4], e[5], e[6], e[7]);
        *(ushort4*)(db + wnt * 512 + lane * 8)     = o0;
        *(ushort4*)(db + wnt * 512 + lane * 8 + 4) = o1;
    }
}

// Fused: per-batch cumsum of duration + per-frame packed gather index
// pk = t | plo<<10 | elo<<19 (or -1 if frame >= total); mel_len.
__global__ __launch_bounds__(256) void cumsum_idx_kernel(
    const int* __restrict__ dur,
    const float* __restrict__ pbins, const float* __restrict__ ptgt,
    const float* __restrict__ ebins, const float* __restrict__ etgt,
    int* __restrict__ xidx, float* __restrict__ mel_len)
{
    __shared__ int cs[T_];
    __shared__ int part[256];
    __shared__ float pb[NBINS_], eb[NBINS_];
    const int b = blockIdx.x;
    const int tid = threadIdx.x;
    if (tid < NBINS_) { pb[tid] = pbins[tid]; eb[tid] = ebins[tid]; }
    int l[4];
    int s = 0;
#pragma unroll
    for (int i = 0; i < 4; ++i) { l[i] = dur[(b << 10) + tid * 4 + i]; s += l[i]; }
    part[tid] = s;
    __syncthreads();
    for (int off = 1; off < 256; off <<= 1) {
        int u = 0;
        if (tid >= off) u = part[tid - off];
        __syncthreads();
        part[tid] += u;
        __syncthreads();
    }
    const int incl = part[tid];
    int run = incl - s;
#pragma unroll
    for (int i = 0; i < 4; ++i) {
        run += l[i];
        cs[tid * 4 + i] = run;
    }
    if (tid == 255) mel_len[b] = (float)incl;
    __syncthreads();
    const int total = cs[T_ - 1];
    for (int f = tid; f < MAXLEN_; f += 256) {
        int pk = -1;
        if (f < total) {
            int lo = 0, hi = T_;
            while (lo < hi) {
                const int mid = (lo + hi) >> 1;
                if (cs[mid] <= f) lo = mid + 1; else hi = mid;
            }
            const int t = lo > T_ - 1 ? T_ - 1 : lo;
            const int row = (b << 10) + t;
            const float ptg = ptgt[row];
            int plo = 0, phi = NBINS_;
            while (plo < phi) {
                const int mid = (plo + phi) >> 1;
                if (pb[mid] < ptg) plo = mid + 1; else phi = mid;
            }
            const float etg = etgt[row];
            int elo = 0, ehi = NBINS_;
            while (elo < ehi) {
                const int mid = (elo + ehi) >> 1;
                if (eb[mid] < etg) elo = mid + 1; else ehi = mid;
            }
            pk = t | (plo << 10) | (elo << 19);
        }
        xidx[(b << 11) + f] = pk;
    }
}

// out[b,frame,:] = pk<0 ? 0 : x[b,t,:] + pemb[plo] + eemb[elo]  (fp32 exact)
__global__ __launch_bounds__(256) void length_reg_kernel(
    const float* __restrict__ x, const int* __restrict__ xidx,
    const float* __restrict__ pemb, const float* __restrict__ eemb,
    float* __restrict__ out)
{
    const int g    = blockIdx.x * 256 + threadIdx.x;  // B*2048*96
    const int c4   = g % 96;
    const int rest = g / 96;
    const int frame = rest & (MAXLEN_ - 1);
    const int b     = rest >> 11;
    const int pk = xidx[(b << 11) + frame];
    float4 v = make_float4(0.f, 0.f, 0.f, 0.f);
    if (pk >= 0) {
        const int t   = pk & 1023;
        const int plo = (pk >> 10) & 511;
        const int elo = (pk >> 19) & 511;
        v = *(const float4*)(x + ((size_t)(b << 10) + t) * C_ + c4 * 4);
        const float4 pe = *(const float4*)(pemb + (size_t)plo * C_ + c4 * 4);
        const float4 ee = *(const float4*)(eemb + (size_t)elo * C_ + c4 * 4);
        v.x += pe.x + ee.x; v.y += pe.y + ee.y;
        v.z += pe.z + ee.z; v.w += pe.w + ee.w;
    }
    *(float4*)(out + (size_t)g * 4) = v;
}

extern "C" void kernel_launch(void* const* d_in, const int* in_sizes, int n_in,
                              void* d_out, int out_size, void* d_ws, size_t ws_size,
                              hipStream_t stream)
{
    const float* x        = (const float*)d_in[0];
    const int*   duration = (const int*)d_in[2];
    const float* P[3][10];
    for (int p = 0; p < 3; ++p)
        for (int q = 0; q < 10; ++q)
            P[p][q] = (const float*)d_in[4 + p * 10 + q];
    const float* pitch_bins    = (const float*)d_in[34];
    const float* energy_bins   = (const float*)d_in[35];
    const float* pitch_emb     = (const float*)d_in[36];
    const float* energy_emb    = (const float*)d_in[37];
    const float* pitch_target  = (const float*)d_in[38];
    const float* energy_target = (const float*)d_in[39];

    float* out_x      = (float*)d_out;                       // (B,2048,384)
    float* out_pitch  = out_x + (size_t)B_ * MAXLEN_ * C_;
    float* out_energy = out_pitch + B_ * T_;
    float* out_logdur = out_energy + B_ * T_;
    float* out_mellen = out_logdur + B_ * T_;

    unsigned short* wpk = (unsigned short*)d_ws;             // 6*WPK1 bf16
    int* xidx = (int*)(wpk + (size_t)6 * WPK1);              // B*2048 ints

    const dim3 blk(256);
    const dim3 cblk(512);

    pack_w_kernel<<<216, blk, 0, stream>>>(
        P[0][0], P[0][4], P[1][0], P[1][4], P[2][0], P[2][4], wpk);

    CvP Pa;
    Pa.xf = x; Pa.wpk = wpk;
    for (int p = 0; p < 3; ++p) {
        Pa.b1[p]  = P[p][1];
        Pa.g1[p]  = P[p][2];
        Pa.be1[p] = P[p][3];
        Pa.b2[p]  = P[p][5];
        Pa.g2[p]  = P[p][6];
        Pa.be2[p] = P[p][7];
        Pa.wo[p]  = P[p][8];
        Pa.bo[p]  = P[p][9];
    }
    Pa.pred[0] = out_logdur; Pa.pred[1] = out_pitch; Pa.pred[2] = out_energy;
    Pa.pbins = pitch_bins; Pa.pemb = pitch_emb; Pa.ptgt = pitch_target;

    conv_fused3<<<3 * B_ * NTILE, cblk, 0, stream>>>(Pa);

    cumsum_idx_kernel<<<B_, blk, 0, stream>>>(
        duration, pitch_bins, pitch_target, energy_bins, energy_target,
        xidx, out_mellen);
    length_reg_kernel<<<24576, blk, 0, stream>>>(
        x, xidx, pitch_emb, energy_emb, out_x);
}